// Round 1
// baseline (1286.068 us; speedup 1.0000x reference)
//
#include <hip/hip_runtime.h>
#include <hip/hip_bf16.h>
#include <math.h>

#define NR 32768
#define DD 384
#define CDM 882

typedef float f4 __attribute__((ext_vector_type(4)));
typedef float f32x4 __attribute__((ext_vector_type(4)));
typedef __bf16 bf16x8 __attribute__((ext_vector_type(8)));
typedef __bf16 bf16x4 __attribute__((ext_vector_type(4)));

__device__ inline f4 ld4(const float* p) { f4 v; __builtin_memcpy(&v, p, 16); return v; }
__device__ inline bf16x8 ld8h(const __bf16* p) { bf16x8 v; __builtin_memcpy(&v, p, 16); return v; }

__device__ inline float wred(float v) {
#pragma unroll
  for (int o = 32; o > 0; o >>= 1) v += __shfl_xor(v, o, 64);
  return v;
}

// ---------------- weight transpose: W[K][DD] fp32 -> WT[DD][K] bf16 ----------------
__global__ __launch_bounds__(256) void trans_k(const float* __restrict__ W,
                                               __bf16* __restrict__ WT, int K) {
  int i = blockIdx.x * 256 + threadIdx.x;
  if (i >= K * DD) return;
  int k = i / DD, n = i - k * DD;
  WT[(size_t)n * K + k] = (__bf16)W[i];
}

// ---------------- generic MFMA GEMM: OUT[M,384] = epi(A[M,K] @ W[K,384] + bias) ----
// EPI: 0 = store, 1 = relu, 2 = OUT += v (residual in-place), 3 = gated:
//      OUT[o] = XRES[o] + sigmoid(OUT[o]) * v   (OUT holds gate logits, in-place)
template <int EPI>
__global__ __launch_bounds__(256, 2) void gemm_k(
    const float* __restrict__ A, const __bf16* __restrict__ WT,
    const float* __restrict__ bias, float* __restrict__ OUT,
    const float* __restrict__ XRES, const int* __restrict__ idx, int M, int K) {
  __shared__ __align__(16) __bf16 As[128][72];
  __shared__ __align__(16) __bf16 Bs[128][72];
  const int t = threadIdx.x;
  const int m0 = blockIdx.x * 128;
  const int n0 = blockIdx.y * 128;

  const int r0 = t >> 4;        // A-stage: row group 0..15
  const int c4 = t & 15;        // A-stage: float4 index within 64-col tile
  int arow[8];
#pragma unroll
  for (int i = 0; i < 8; ++i) {
    int gm = m0 + r0 + 16 * i;
    arow[i] = idx ? idx[gm] : gm;  // idx<0 -> masked (zero row)
  }
  const int bn = t >> 3;        // B-stage: row group 0..31
  const int bk = (t & 7) * 8;   // B-stage: k chunk (8 bf16 = 16B)

  f32x4 acc[4][4];
#pragma unroll
  for (int a = 0; a < 4; ++a)
#pragma unroll
    for (int b = 0; b < 4; ++b)
#pragma unroll
      for (int j = 0; j < 4; ++j) acc[a][b][j] = 0.f;

  const int w = t >> 6, lane = t & 63;
  const int wr = (w >> 1) * 64, wc = (w & 1) * 64;
  const int fr = lane & 15, fq = lane >> 4;

  for (int k0 = 0; k0 < K; k0 += 64) {
    // stage A (fp32 -> bf16)
    {
      int k = k0 + c4 * 4;
#pragma unroll
      for (int i = 0; i < 8; ++i) {
        f4 v;
#pragma unroll
        for (int e = 0; e < 4; ++e) v[e] = 0.f;
        if (arow[i] >= 0) {
          const float* ap = A + (size_t)arow[i] * K + k;
          if (k + 4 <= K) {
            v = ld4(ap);
          } else {
#pragma unroll
            for (int e = 0; e < 4; ++e)
              if (k + e < K) v[e] = ap[e];
          }
        }
        bf16x4 h = __builtin_convertvector(v, bf16x4);
        *reinterpret_cast<bf16x4*>(&As[r0 + 16 * i][c4 * 4]) = h;
      }
    }
    // stage B (already bf16, transposed: WT[n][k])
    {
      int k = k0 + bk;
#pragma unroll
      for (int p = 0; p < 4; ++p) {
        int n = bn + 32 * p;
        const __bf16* wp = WT + (size_t)(n0 + n) * K + k;
        bf16x8 v;
        if (k + 8 <= K) {
          v = ld8h(wp);
        } else {
#pragma unroll
          for (int e = 0; e < 8; ++e) v[e] = (k + e < K) ? wp[e] : (__bf16)0.f;
        }
        *reinterpret_cast<bf16x8*>(&Bs[n][bk]) = v;
      }
    }
    __syncthreads();
#pragma unroll
    for (int kk = 0; kk < 64; kk += 32) {
      bf16x8 af[4], bv[4];
#pragma unroll
      for (int mi = 0; mi < 4; ++mi)
        af[mi] = *reinterpret_cast<const bf16x8*>(&As[wr + mi * 16 + fr][kk + fq * 8]);
#pragma unroll
      for (int ni = 0; ni < 4; ++ni)
        bv[ni] = *reinterpret_cast<const bf16x8*>(&Bs[wc + ni * 16 + fr][kk + fq * 8]);
#pragma unroll
      for (int mi = 0; mi < 4; ++mi)
#pragma unroll
        for (int ni = 0; ni < 4; ++ni)
          acc[mi][ni] = __builtin_amdgcn_mfma_f32_16x16x32_bf16(af[mi], bv[ni],
                                                                acc[mi][ni], 0, 0, 0);
    }
    __syncthreads();
  }

#pragma unroll
  for (int mi = 0; mi < 4; ++mi) {
#pragma unroll
    for (int ni = 0; ni < 4; ++ni) {
      int col = n0 + wc + ni * 16 + fr;
      float bvv = bias[col];
#pragma unroll
      for (int j = 0; j < 4; ++j) {
        int row = m0 + wr + mi * 16 + fq * 4 + j;
        size_t o = (size_t)row * DD + col;
        float v = acc[mi][ni][j] + bvv;
        if constexpr (EPI == 0) {
          OUT[o] = v;
        } else if constexpr (EPI == 1) {
          OUT[o] = fmaxf(v, 0.f);
        } else if constexpr (EPI == 2) {
          OUT[o] += v;
        } else {
          float gl = OUT[o];
          float g = 1.f / (1.f + expf(-gl));
          OUT[o] = XRES[o] + g * v;
        }
      }
    }
  }
}

// ---------------- LayerNorm (eps = 1e-3), one wave per row ----------------
// MODE 0: out = LN(x1)*g+b ; MODE 1: out = relu(LN(x1)*g+b) ; MODE 2: out = LN(x1+x2+x3)*g+b
template <int MODE>
__global__ __launch_bounds__(256) void ln_k(const float* __restrict__ x1,
                                            const float* __restrict__ x2,
                                            const float* __restrict__ x3,
                                            const float* __restrict__ g,
                                            const float* __restrict__ b,
                                            float* __restrict__ out) {
  int row = blockIdx.x * 4 + (threadIdx.x >> 6);
  int lane = threadIdx.x & 63;
  size_t base = (size_t)row * DD;
  float v[6];
#pragma unroll
  for (int i = 0; i < 6; ++i) {
    int c = lane + 64 * i;
    float x = x1[base + c];
    if constexpr (MODE == 2) x += x2[base + c] + x3[base + c];
    v[i] = x;
  }
  float s = 0.f;
#pragma unroll
  for (int i = 0; i < 6; ++i) s += v[i];
  s = wred(s);
  float mean = s * (1.f / 384.f);
  float q = 0.f;
#pragma unroll
  for (int i = 0; i < 6; ++i) { float d = v[i] - mean; q += d * d; }
  q = wred(q);
  float rs = rsqrtf(q * (1.f / 384.f) + 1e-3f);
#pragma unroll
  for (int i = 0; i < 6; ++i) {
    int c = lane + 64 * i;
    float y = (v[i] - mean) * rs * g[c] + b[c];
    if constexpr (MODE == 1) y = fmaxf(y, 0.f);
    out[base + c] = y;
  }
}

// ---------------- segment softmax helpers ----------------
__device__ inline unsigned fenc(float f) {
  unsigned u = __float_as_uint(f);
  return (u & 0x80000000u) ? ~u : (u | 0x80000000u);
}
__device__ inline float fdec(unsigned u) {
  unsigned b = (u & 0x80000000u) ? (u ^ 0x80000000u) : ~u;
  return __uint_as_float(b);
}

__global__ __launch_bounds__(256) void segmax_k(const float* __restrict__ L,
                                                const int* __restrict__ gid,
                                                unsigned* __restrict__ gmax, int total) {
  int i = blockIdx.x * 256 + threadIdx.x;
  if (i >= total) return;
  int m = i / DD, c = i - m * DD;
  atomicMax(&gmax[(size_t)gid[m] * DD + c], fenc(L[i]));
}

__global__ __launch_bounds__(256) void segexp_k(float* __restrict__ L,
                                                const int* __restrict__ gid,
                                                const unsigned* __restrict__ gmax,
                                                float* __restrict__ den, int total) {
  int i = blockIdx.x * 256 + threadIdx.x;
  if (i >= total) return;
  int m = i / DD, c = i - m * DD;
  size_t go = (size_t)gid[m] * DD + c;
  float e = expf(L[i] - fdec(gmax[go]));
  L[i] = e;
  atomicAdd(&den[go], e);
}

__global__ __launch_bounds__(256) void segwsum_k(const float* __restrict__ E,
                                                 const float* __restrict__ F,
                                                 const int* __restrict__ gid,
                                                 const float* __restrict__ den,
                                                 float* __restrict__ y, int total) {
  int i = blockIdx.x * 256 + threadIdx.x;
  if (i >= total) return;
  int m = i / DD, c = i - m * DD;
  size_t go = (size_t)gid[m] * DD + c;
  float w = E[i] / (den[go] + 1e-12f);
  atomicAdd(&y[go], F[i] * w);
}

__global__ __launch_bounds__(256) void addgather_k(float* __restrict__ X,
                                                   const float* __restrict__ z,
                                                   const int* __restrict__ gid, int total) {
  int i = blockIdx.x * 256 + threadIdx.x;
  if (i >= total) return;
  int m = i / DD, c = i - m * DD;
  X[i] += z[(size_t)gid[m] * DD + c];
}

// ---------------- final: write net, d = r@dw+db, w = sigmoid(r@ww+wb) ----------------
__global__ __launch_bounds__(256) void final_k(const float* __restrict__ net,
                                               const float* __restrict__ dw,
                                               const float* __restrict__ db,
                                               const float* __restrict__ ww,
                                               const float* __restrict__ wb,
                                               float* __restrict__ out) {
  int row = blockIdx.x * 4 + (threadIdx.x >> 6);
  int lane = threadIdx.x & 63;
  size_t base = (size_t)row * DD;
  float d0 = 0.f, d1 = 0.f, w0 = 0.f, w1 = 0.f;
#pragma unroll
  for (int i = 0; i < 6; ++i) {
    int c = lane + 64 * i;
    float x = net[base + c];
    out[base + c] = x;
    float r = fmaxf(x, 0.f);
    d0 += r * dw[2 * c];
    d1 += r * dw[2 * c + 1];
    w0 += r * ww[2 * c];
    w1 += r * ww[2 * c + 1];
  }
  d0 = wred(d0); d1 = wred(d1); w0 = wred(w0); w1 = wred(w1);
  if (lane == 0) {
    float* outd = out + (size_t)NR * DD;
    float* outw = outd + (size_t)NR * 2;
    outd[2 * row] = d0 + db[0];
    outd[2 * row + 1] = d1 + db[1];
    outw[2 * row] = 1.f / (1.f + expf(-(w0 + wb[0])));
    outw[2 * row + 1] = 1.f / (1.f + expf(-(w1 + wb[1])));
  }
}

extern "C" void kernel_launch(void* const* d_in, const int* in_sizes, int n_in,
                              void* d_out, int out_size, void* d_ws, size_t ws_size,
                              hipStream_t stream) {
  const float* in_net = (const float*)d_in[0];
  const float* in_inp = (const float*)d_in[1];
  const float* in_corr = (const float*)d_in[2];
  const int* nix = (const int*)d_in[3];
  const int* njx = (const int*)d_in[4];
  const int* ukk = (const int*)d_in[5];
  const int* ujk = (const int*)d_in[6];
  auto F = [&](int i) { return (const float*)d_in[i]; };

  constexpr size_t SZ_BIG = (size_t)NR * DD * 4;      // 50,331,648
  constexpr size_t SZ_SEG = (size_t)4096 * DD * 4;    // 6,291,456
  char* ws = (char*)d_ws;
  float* T1 = (float*)(ws);
  float* T2 = (float*)(ws + SZ_BIG);
  unsigned* gmax = (unsigned*)(ws + 2 * SZ_BIG);
  float* den = (float*)(ws + 2 * SZ_BIG + SZ_SEG);
  float* yb = (float*)(ws + 2 * SZ_BIG + 2 * SZ_SEG);
  float* zb = (float*)(ws + 2 * SZ_BIG + 3 * SZ_SEG);
  __bf16* wtp = (__bf16*)(ws + 2 * SZ_BIG + 4 * SZ_SEG);
  float* T3 = (float*)d_out;  // net region of output doubles as big scratch

  __bf16* wt_corr1 = wtp; wtp += (size_t)CDM * DD;
  auto nxt = [&]() { __bf16* p = wtp; wtp += (size_t)DD * DD; return p; };
  __bf16 *wt_corr2 = nxt(), *wt_corr3 = nxt(), *wt_c1a = nxt(), *wt_c1b = nxt(),
         *wt_c2a = nxt(), *wt_c2b = nxt(), *wt_kkf = nxt(), *wt_kkg = nxt(),
         *wt_kkh = nxt(), *wt_ijf = nxt(), *wt_ijg = nxt(), *wt_ijh = nxt(),
         *wt_g1g = nxt(), *wt_g1r1 = nxt(), *wt_g1r2 = nxt(), *wt_g2g = nxt(),
         *wt_g2r1 = nxt(), *wt_g2r2 = nxt();

  auto TR = [&](int wi, __bf16* dst, int K) {
    int tot = K * DD;
    trans_k<<<(tot + 255) / 256, 256, 0, stream>>>(F(wi), dst, K);
  };
  TR(7, wt_corr1, CDM); TR(9, wt_corr2, DD); TR(13, wt_corr3, DD);
  TR(17, wt_c1a, DD); TR(19, wt_c1b, DD); TR(21, wt_c2a, DD); TR(23, wt_c2b, DD);
  TR(25, wt_kkf, DD); TR(27, wt_kkg, DD); TR(29, wt_kkh, DD);
  TR(31, wt_ijf, DD); TR(33, wt_ijg, DD); TR(35, wt_ijh, DD);
  TR(39, wt_g1g, DD); TR(41, wt_g1r1, DD); TR(43, wt_g1r2, DD);
  TR(47, wt_g2g, DD); TR(49, wt_g2r1, DD); TR(51, wt_g2r2, DD);

  auto GEMM = [&](int epi, const float* A, const __bf16* WT, const float* bias,
                  float* OUT, const float* XRES, const int* idx, int M, int K) {
    dim3 g(M / 128, 3), b(256);
    switch (epi) {
      case 0: gemm_k<0><<<g, b, 0, stream>>>(A, WT, bias, OUT, XRES, idx, M, K); break;
      case 1: gemm_k<1><<<g, b, 0, stream>>>(A, WT, bias, OUT, XRES, idx, M, K); break;
      case 2: gemm_k<2><<<g, b, 0, stream>>>(A, WT, bias, OUT, XRES, idx, M, K); break;
      default: gemm_k<3><<<g, b, 0, stream>>>(A, WT, bias, OUT, XRES, idx, M, K); break;
    }
  };
  const int LNG = NR / 4;
  const int TOT = NR * DD;
  const int SEGB = (TOT + 255) / 256;

  // corr encoder
  GEMM(1, in_corr, wt_corr1, F(8), T1, nullptr, nullptr, NR, CDM);
  GEMM(0, T1, wt_corr2, F(10), T2, nullptr, nullptr, NR, DD);
  ln_k<1><<<LNG, 256, 0, stream>>>(T2, nullptr, nullptr, F(11), F(12), T1);
  GEMM(0, T1, wt_corr3, F(14), T2, nullptr, nullptr, NR, DD);
  // net = LN(net + inp + h)
  ln_k<2><<<LNG, 256, 0, stream>>>(in_net, in_inp, T2, F(15), F(16), T1);
  // c1: net += MLP2(mask * net[nix])
  GEMM(1, T1, wt_c1a, F(18), T2, nullptr, nix, NR, DD);
  GEMM(2, T2, wt_c1b, F(20), T1, nullptr, nullptr, NR, DD);
  // c2: net += MLP2(mask * net[njx])
  GEMM(1, T1, wt_c2a, F(22), T2, nullptr, njx, NR, DD);
  GEMM(2, T2, wt_c2b, F(24), T1, nullptr, nullptr, NR, DD);
  // kk soft-agg (G=4096)
  GEMM(0, T1, wt_kkg, F(28), T2, nullptr, nullptr, NR, DD);  // logits
  GEMM(0, T1, wt_kkf, F(26), T3, nullptr, nullptr, NR, DD);  // feats
  hipMemsetAsync(gmax, 0, (size_t)4096 * DD * 4, stream);
  hipMemsetAsync(den, 0, (size_t)4096 * DD * 4, stream);
  hipMemsetAsync(yb, 0, (size_t)4096 * DD * 4, stream);
  segmax_k<<<SEGB, 256, 0, stream>>>(T2, ukk, gmax, TOT);
  segexp_k<<<SEGB, 256, 0, stream>>>(T2, ukk, gmax, den, TOT);
  segwsum_k<<<SEGB, 256, 0, stream>>>(T2, T3, ukk, den, yb, TOT);
  GEMM(0, yb, wt_kkh, F(30), zb, nullptr, nullptr, 4096, DD);
  addgather_k<<<SEGB, 256, 0, stream>>>(T1, zb, ukk, TOT);
  // ij soft-agg (G=512)
  GEMM(0, T1, wt_ijg, F(34), T2, nullptr, nullptr, NR, DD);
  GEMM(0, T1, wt_ijf, F(32), T3, nullptr, nullptr, NR, DD);
  hipMemsetAsync(gmax, 0, (size_t)512 * DD * 4, stream);
  hipMemsetAsync(den, 0, (size_t)512 * DD * 4, stream);
  hipMemsetAsync(yb, 0, (size_t)512 * DD * 4, stream);
  segmax_k<<<SEGB, 256, 0, stream>>>(T2, ujk, gmax, TOT);
  segexp_k<<<SEGB, 256, 0, stream>>>(T2, ujk, gmax, den, TOT);
  segwsum_k<<<SEGB, 256, 0, stream>>>(T2, T3, ujk, den, yb, TOT);
  GEMM(0, yb, wt_ijh, F(36), zb, nullptr, nullptr, 512, DD);
  addgather_k<<<SEGB, 256, 0, stream>>>(T1, zb, ujk, TOT);
  // gated residual 1
  ln_k<0><<<LNG, 256, 0, stream>>>(T1, nullptr, nullptr, F(37), F(38), T2);  // x = net6
  GEMM(0, T2, wt_g1g, F(40), T3, nullptr, nullptr, NR, DD);                  // gate logits
  GEMM(1, T2, wt_g1r1, F(42), T1, nullptr, nullptr, NR, DD);                 // relu
  GEMM(3, T1, wt_g1r2, F(44), T3, T2, nullptr, NR, DD);                      // T3 = net7
  // gated residual 2
  ln_k<0><<<LNG, 256, 0, stream>>>(T3, nullptr, nullptr, F(45), F(46), T1);  // x = net8
  GEMM(0, T1, wt_g2g, F(48), T2, nullptr, nullptr, NR, DD);
  GEMM(1, T1, wt_g2r1, F(50), T3, nullptr, nullptr, NR, DD);
  GEMM(3, T3, wt_g2r2, F(52), T2, T1, nullptr, NR, DD);                      // T2 = net9
  // outputs
  final_k<<<LNG, 256, 0, stream>>>(T2, F(53), F(54), F(55), F(56), (float*)d_out);
}